// Round 1
// baseline (546.566 us; speedup 1.0000x reference)
//
#include <hip/hip_runtime.h>
#include <math.h>

#define TOKENS   16384
#define HID      4096
#define NE       64
#define BM       64
#define BK       64
#define NKT      (HID / BK)     /* 64 */
#define TOPK     6
#define RSCALE   2.5f

/* single LDS pool, byte-addressed so we can XOR-swizzle offsets.
   As[2][BM*BK] floats at byte 0      (2 * 16 KB)
   Bs[2][NE*BK] floats at byte 32768  (2 * 16 KB)
   Lt[NE][BM+1] floats at byte 65536  (16.25 KB, +1 pad kills bank conflicts) */
#define AS_OFF   0u
#define BS_OFF   32768u
#define LT_OFF   65536u
#define LDS_BYTES (65536 + NE * (BM + 1) * 4)

typedef const __attribute__((address_space(1))) void* gptr_t;
typedef __attribute__((address_space(3))) void* sptr_t;

__global__ __launch_bounds__(256, 1)
void TinyTopkRouter_18923625906578_kernel(const float* __restrict__ x,
                                          const float* __restrict__ w,
                                          float* __restrict__ out)
{
    __shared__ char lds[LDS_BYTES];

    const int tid  = threadIdx.x;
    const int wav  = tid >> 6;
    const int lane = tid & 63;
    const int tx   = tid & 15;   /* expert group: experts tx + 16*i   */
    const int ty   = tid >> 4;   /* row group:    rows   ty*4 + r     */
    const int m0   = blockIdx.x * BM;

    /* ---- staging geometry (per lane): 1 KB per wave-instruction, 4 rows each.
       Source address carries the inverse swizzle; LDS dest stays linear
       (global_load_lds writes base + lane*16). */
    const int srow = lane >> 4;   /* row within instruction, 0..3 */
    const int sc   = lane & 15;   /* 16-byte chunk, 0..15         */
    unsigned g_off[4];
    int      grow[4];
    #pragma unroll
    for (int i = 0; i < 4; ++i) {
        int ii  = wav * 4 + i;
        int row = ii * 4 + srow;
        unsigned sw4 = (unsigned)(((row >> 1) & 7) << 4);   /* swizzle in bytes */
        grow[i]  = row;
        g_off[i] = ((unsigned)(sc << 4)) ^ sw4;             /* byte offset in row */
    }

    auto stage = [&](int buf, int k0) {
        #pragma unroll
        for (int i = 0; i < 4; ++i) {
            const int ii = wav * 4 + i;
            const char* gA = (const char*)(x + (size_t)(m0 + grow[i]) * HID + k0) + g_off[i];
            char* lA = &lds[AS_OFF + (unsigned)buf * (BM * BK * 4) + (unsigned)ii * 1024];
            __builtin_amdgcn_global_load_lds((gptr_t)gA, (sptr_t)lA, 16, 0, 0);
            const char* gB = (const char*)(w + (size_t)grow[i] * HID + k0) + g_off[i];
            char* lB = &lds[BS_OFF + (unsigned)buf * (NE * BK * 4) + (unsigned)ii * 1024];
            __builtin_amdgcn_global_load_lds((gptr_t)gB, (sptr_t)lB, 16, 0, 0);
        }
    };

    /* ---- per-thread LDS read bases (byte offsets, swizzle folded in) ----
       read address = (base + buf_off) ^ (kk*4); XOR bits 3..7 never collide
       with the row-base bits (>=8) because sw4 is bits 4..6 and bit 3/7 of
       base are zero. */
    unsigned a_base[4], b_base[4];
    #pragma unroll
    for (int r = 0; r < 4; ++r) {
        int m = ty * 4 + r;
        a_base[r] = AS_OFF + (unsigned)m * 256u + (unsigned)(((m >> 1) & 7) << 4);
    }
    #pragma unroll
    for (int i = 0; i < 4; ++i) {
        int e = i * 16 + tx;
        b_base[i] = BS_OFF + (unsigned)e * 256u + (unsigned)(((e >> 1) & 7) << 4);
    }

    double accd[4][4];
    #pragma unroll
    for (int r = 0; r < 4; ++r)
        #pragma unroll
        for (int i = 0; i < 4; ++i) accd[r][i] = 0.0;

    stage(0, 0);
    __syncthreads();
    int buf = 0;
    for (int kt = 0; kt < NKT; ++kt) {
        if (kt + 1 < NKT) stage(buf ^ 1, (kt + 1) * BK);

        const unsigned abuf = (unsigned)buf * (BM * BK * 4);
        const unsigned bbuf = (unsigned)buf * (NE * BK * 4);
        float acc[4][4] = {{0.f, 0.f, 0.f, 0.f}, {0.f, 0.f, 0.f, 0.f},
                           {0.f, 0.f, 0.f, 0.f}, {0.f, 0.f, 0.f, 0.f}};
        #pragma unroll
        for (int kk = 0; kk < BK; kk += 2) {
            float2 av[4], bv[4];
            #pragma unroll
            for (int r = 0; r < 4; ++r)
                av[r] = *(const float2*)&lds[(a_base[r] + abuf) ^ (unsigned)(kk << 2)];
            #pragma unroll
            for (int i = 0; i < 4; ++i)
                bv[i] = *(const float2*)&lds[(b_base[i] + bbuf) ^ (unsigned)(kk << 2)];
            #pragma unroll
            for (int r = 0; r < 4; ++r)
                #pragma unroll
                for (int i = 0; i < 4; ++i)
                    acc[r][i] += av[r].x * bv[i].x + av[r].y * bv[i].y;
        }
        /* fp64 master accumulation: keeps our logits ~3e-8 from exact so
           top-k ordering matches the fp32 numpy reference as closely as
           physically possible (index flips are the failure mode here). */
        #pragma unroll
        for (int r = 0; r < 4; ++r)
            #pragma unroll
            for (int i = 0; i < 4; ++i)
                accd[r][i] += (double)acc[r][i];
        __syncthreads();
        buf ^= 1;
    }

    /* ---- epilogue: logits -> LDS transposed [expert][token], padded ---- */
    float* Lt = (float*)&lds[LT_OFF];
    #pragma unroll
    for (int r = 0; r < 4; ++r)
        #pragma unroll
        for (int i = 0; i < 4; ++i)
            Lt[(i * 16 + tx) * (BM + 1) + (ty * 4 + r)] = (float)accd[r][i];
    __syncthreads();

    if (tid < BM) {
        const int m     = tid;
        const int token = m0 + m;
        float l[NE];
        #pragma unroll
        for (int e = 0; e < NE; ++e) l[e] = Lt[e * (BM + 1) + m];

        float mx = l[0];
        #pragma unroll
        for (int e = 1; e < NE; ++e) mx = fmaxf(mx, l[e]);
        float denom = 0.f;
        #pragma unroll
        for (int e = 0; e < NE; ++e) denom += expf(l[e] - mx);
        const float invd = RSCALE / denom;

        float* out_idx = out;
        float* out_w   = out + (size_t)TOKENS * TOPK;
        unsigned long long used = 0ull;
        for (int j = 0; j < TOPK; ++j) {
            float bvv = -3.4e38f;
            int   bi  = 0;
            #pragma unroll
            for (int e = 0; e < NE; ++e) {
                /* strict '>' keeps the LOWEST index among ties, matching
                   jax.lax.top_k tie-breaking */
                bool ok = (((used >> e) & 1ull) == 0ull) && (l[e] > bvv);
                bvv = ok ? l[e] : bvv;
                bi  = ok ? e    : bi;
            }
            used |= (1ull << bi);
            out_idx[(size_t)token * TOPK + j] = (float)bi;  /* harness reads buffer as f32 */
            out_w  [(size_t)token * TOPK + j] = expf(bvv - mx) * invd;
        }
    }
}

extern "C" void kernel_launch(void* const* d_in, const int* in_sizes, int n_in,
                              void* d_out, int out_size, void* d_ws, size_t ws_size,
                              hipStream_t stream) {
    const float* x = (const float*)d_in[0];
    const float* w = (const float*)d_in[1];
    float* out = (float*)d_out;
    dim3 grid(TOKENS / BM);   /* 256 blocks -> 1 per CU */
    dim3 block(256);
    hipLaunchKernelGGL(TinyTopkRouter_18923625906578_kernel, grid, block, 0, stream,
                       x, w, out);
}

// Round 2
// 540.430 us; speedup vs baseline: 1.0114x; 1.0114x over previous
//
#include <hip/hip_runtime.h>
#include <math.h>

#define TOKENS 16384
#define HID    4096
#define NE     64
#define BM     64                  /* tokens per block (= lanes) */
#define BK     32                  /* k per tile */
#define KG     4                   /* K-split groups (waves) */
#define KRANGE (HID / KG)          /* 1024 */
#define NT     (KRANGE / BK)       /* 32 tiles per k-group */
#define TOPK   6
#define RSCALE 2.5f

#define TILE_BYTES (BM * BK * 4)   /* 8192 */
#define NBUF 3                     /* triple buffer: stage target's readers finished a barrier ago */
#define LDS_BYTES (KG * NBUF * TILE_BYTES)   /* 96 KB; epilogue Lp[4][64][64] f32 = 64 KB aliases */

typedef const __attribute__((address_space(1))) void* gptr_t;
typedef __attribute__((address_space(3))) void* sptr_t;

extern __shared__ char lds[];

/* ---------------- pre-kernel: wT[k][e] = w[e][k] into d_ws (1 MB) -------- */
__global__ __launch_bounds__(256)
void wtrans_kernel(const float* __restrict__ w, float* __restrict__ wT)
{
    int o = blockIdx.x * 256 + threadIdx.x;       /* 0..65535 */
    #pragma unroll
    for (int j = 0; j < 4; ++j) {
        int idx = o + j * 65536;                  /* 0..262143 */
        int k = idx >> 6, e = idx & 63;
        wT[idx] = w[e * HID + k];
    }
}

/* ---------------- main kernel ------------------------------------------- */
__global__ __launch_bounds__(1024)
void TinyTopkRouter_18923625906578_kernel(const float* __restrict__ x,
                                          const float* __restrict__ wT,
                                          float* __restrict__ out)
{
    const int tid  = threadIdx.x;
    const int wave = tid >> 6;
    const int lane = tid & 63;          /* lane = token within block */
    const int kg   = wave >> 2;         /* 0..3 : K-split group  */
    const int eg   = wave & 3;          /* 0..3 : expert group   */
    const int m0   = blockIdx.x * BM;
    /* force scalar (SGPR) addressing for weight loads */
    const int eg_s = __builtin_amdgcn_readfirstlane(eg);
    const int kg_s = __builtin_amdgcn_readfirstlane(kg);

    /* ---- staging geometry: tile (8 KB) = 8 wave-instrs of 1 KB.
       wave eg does instrs i = eg*2+it; lane -> row = 8i + (lane>>3),
       chunk c = lane&7; source k-chunk q = c ^ (row&7) (inverse swizzle on
       the GLOBAL address; LDS dest stays linear per global_load_lds rules). */
    const float* gsrc[2];
    unsigned     ldst[2];
    #pragma unroll
    for (int it = 0; it < 2; ++it) {
        int ii  = eg * 2 + it;
        int row = ii * 8 + (lane >> 3);
        int q   = (lane & 7) ^ (row & 7);
        gsrc[it] = x + (size_t)(m0 + row) * HID + kg * KRANGE + q * 4;
        ldst[it] = (unsigned)ii * 1024u;
    }

    auto stage = [&](int buf, int kt) {
        const unsigned tb = (unsigned)((kg * NBUF + buf) * TILE_BYTES);
        #pragma unroll
        for (int it = 0; it < 2; ++it) {
            const float* g = gsrc[it] + kt * BK;
            char* l = &lds[tb + ldst[it]];
            __builtin_amdgcn_global_load_lds((gptr_t)g, (sptr_t)l, 16, 0, 0);
        }
    };

    float  acc32[16];
    double accd[16];
    #pragma unroll
    for (int e = 0; e < 16; ++e) accd[e] = 0.0;

    /* per-lane swizzled read base within a tile */
    const unsigned rb = (unsigned)lane * 128u + (unsigned)((lane & 7) << 4);

    auto compute = [&](int buf, int kt) {
        const unsigned tb = (unsigned)((kg * NBUF + buf) * TILE_BYTES) + rb;
        const float* wrow = wT + (size_t)(kg_s * KRANGE + kt * BK) * NE + eg_s * 16;
        #pragma unroll
        for (int e = 0; e < 16; ++e) acc32[e] = 0.f;
        #pragma unroll
        for (int q = 0; q < 8; ++q) {
            float4 a4 = *(const float4*)&lds[tb ^ (unsigned)(q << 4)];
            float av[4] = {a4.x, a4.y, a4.z, a4.w};
            #pragma unroll
            for (int kq = 0; kq < 4; ++kq) {
                const float* srow = wrow + (q * 4 + kq) * NE;   /* uniform -> s_load */
                #pragma unroll
                for (int e = 0; e < 16; ++e)
                    acc32[e] = fmaf(av[kq], srow[e], acc32[e]);
            }
        }
        /* fp64 master: keep fp32 chains at 32 elements (matches passing R1) */
        #pragma unroll
        for (int e = 0; e < 16; ++e) accd[e] += (double)acc32[e];
    };

    /* ---- pipelined K-loop: stage t_{i+2}; vmcnt(2) => t_{i+1} landed before
       the barrier that opens iteration i+1; compute t_i. Triple-buffered so
       the stage target's readers finished before the previous barrier. */
    stage(0, 0);
    stage(1, 1);
    asm volatile("s_waitcnt vmcnt(2)" ::: "memory");
    __builtin_amdgcn_s_barrier();
    for (int i = 0; i < NT; ++i) {
        if (i + 2 < NT) {
            stage((i + 2) % NBUF, i + 2);
            asm volatile("s_waitcnt vmcnt(2)" ::: "memory");
        } else {
            asm volatile("s_waitcnt vmcnt(0)" ::: "memory");
        }
        compute(i % NBUF, i);
        __builtin_amdgcn_s_barrier();
    }

    /* ---- epilogue: partials -> LDS (aliases A region; all reads done) ---- */
    float* Lp = (float*)lds;                      /* [4 kg][64 e][64 t] */
    #pragma unroll
    for (int e = 0; e < 16; ++e)
        Lp[((kg * NE) + eg * 16 + e) * BM + lane] = (float)accd[e];
    __syncthreads();

    if ((tid & 3) == 0 && tid < 256) {            /* 64 tokens over waves 0..3 */
        const int t     = tid >> 2;
        const int token = m0 + t;
        float l[NE];
        #pragma unroll
        for (int e = 0; e < NE; ++e) {
            float p0 = Lp[(0 * NE + e) * BM + t];
            float p1 = Lp[(1 * NE + e) * BM + t];
            float p2 = Lp[(2 * NE + e) * BM + t];
            float p3 = Lp[(3 * NE + e) * BM + t];
            l[e] = (p0 + p1) + (p2 + p3);
        }
        float mx = l[0];
        #pragma unroll
        for (int e = 1; e < NE; ++e) mx = fmaxf(mx, l[e]);
        float denom = 0.f;
        #pragma unroll
        for (int e = 0; e < NE; ++e) denom += expf(l[e] - mx);
        const float invd = RSCALE / denom;

        float* out_idx = out;
        float* out_w   = out + (size_t)TOKENS * TOPK;
        unsigned long long used = 0ull;
        for (int j = 0; j < TOPK; ++j) {
            float bvv = -3.4e38f;
            int   bi  = 0;
            #pragma unroll
            for (int e = 0; e < NE; ++e) {
                bool ok = (((used >> e) & 1ull) == 0ull) && (l[e] > bvv);
                bvv = ok ? l[e] : bvv;
                bi  = ok ? e    : bi;
            }
            used |= (1ull << bi);
            out_idx[(size_t)token * TOPK + j] = (float)bi;
            out_w  [(size_t)token * TOPK + j] = expf(bvv - mx) * invd;
        }
    }
}

extern "C" void kernel_launch(void* const* d_in, const int* in_sizes, int n_in,
                              void* d_out, int out_size, void* d_ws, size_t ws_size,
                              hipStream_t stream) {
    const float* x = (const float*)d_in[0];
    const float* w = (const float*)d_in[1];
    float* out = (float*)d_out;
    float* wT  = (float*)d_ws;                    /* needs 1 MB of scratch */

    hipFuncSetAttribute((const void*)TinyTopkRouter_18923625906578_kernel,
                        hipFuncAttributeMaxDynamicSharedMemorySize, LDS_BYTES);

    hipLaunchKernelGGL(wtrans_kernel, dim3(256), dim3(256), 0, stream, w, wT);
    hipLaunchKernelGGL(TinyTopkRouter_18923625906578_kernel,
                       dim3(TOKENS / BM), dim3(1024), LDS_BYTES, stream,
                       x, wT, out);
}